// Round 1
// baseline (3105.604 us; speedup 1.0000x reference)
//
#include <hip/hip_runtime.h>
#include <math.h>

#define N_TOK 8192
#define DIM   1024
#define NEXP  8
#define HID   4096
#define CAP   1024
#define TPT   (N_TOK / 256)   // tokens per thread in dispatch kernel = 32

__device__ __forceinline__ float gelu_exact(float v) {
    return 0.5f * v * (1.0f + erff(v * 0.7071067811865476f));
}

// ---------------- router: logits, softmax, argmax, loss accumulators ----------------
__global__ __launch_bounds__(64) void router_kernel(
    const float* __restrict__ x, const float* __restrict__ Wg,
    int* __restrict__ ei, float* __restrict__ eprob,
    float* __restrict__ p_sum, float* __restrict__ z_sum)
{
    const int t = blockIdx.x;
    const int lane = threadIdx.x;
    const float* xr = x + (size_t)t * DIM;
    float acc[NEXP];
#pragma unroll
    for (int e = 0; e < NEXP; ++e) acc[e] = 0.f;
#pragma unroll
    for (int k = 0; k < DIM / 64; ++k) {
        const int d = k * 64 + lane;
        const float xv = xr[d];
        const float4 w0 = *(const float4*)(Wg + (size_t)d * NEXP);
        const float4 w1 = *(const float4*)(Wg + (size_t)d * NEXP + 4);
        acc[0] += xv * w0.x; acc[1] += xv * w0.y;
        acc[2] += xv * w0.z; acc[3] += xv * w0.w;
        acc[4] += xv * w1.x; acc[5] += xv * w1.y;
        acc[6] += xv * w1.z; acc[7] += xv * w1.w;
    }
#pragma unroll
    for (int off = 32; off > 0; off >>= 1) {
#pragma unroll
        for (int e = 0; e < NEXP; ++e)
            acc[e] += __shfl_down(acc[e], off, 64);
    }
    if (lane == 0) {
        float m = acc[0]; int arg = 0;
#pragma unroll
        for (int e = 1; e < NEXP; ++e) { if (acc[e] > m) { m = acc[e]; arg = e; } }
        float ex[NEXP]; float se = 0.f;
#pragma unroll
        for (int e = 0; e < NEXP; ++e) { ex[e] = expf(acc[e] - m); se += ex[e]; }
        const float lse = m + logf(se);
        const float inv = 1.f / se;
#pragma unroll
        for (int e = 0; e < NEXP; ++e) atomicAdd(&p_sum[e], ex[e] * inv);
        atomicAdd(z_sum, lse * lse);
        ei[t] = arg;
        eprob[t] = ex[arg] * inv;
    }
}

// ---------------- dispatch: stable ranks, sort_idx, capacity, aux loss ----------------
__global__ __launch_bounds__(256) void dispatch_kernel(
    const int* __restrict__ ei, const float* __restrict__ eprob,
    int* __restrict__ slot_to_token, int* __restrict__ sort_idx,
    float* __restrict__ scale,
    const float* __restrict__ p_sum, const float* __restrict__ z_sum,
    float* __restrict__ aux_out)
{
    __shared__ int hist[NEXP][256];
    __shared__ int start_s[NEXP];
    const int t = threadIdx.x;
    int le[TPT];
    int lh[NEXP];
#pragma unroll
    for (int e = 0; e < NEXP; ++e) lh[e] = 0;
    const int base = t * TPT;
    for (int i = 0; i < TPT; ++i) {
        const int e = ei[base + i];
        le[i] = e;
        lh[e]++;
    }
#pragma unroll
    for (int e = 0; e < NEXP; ++e) hist[e][t] = lh[e];
    __syncthreads();
    // inclusive Hillis-Steele scan across the 256 threads, per expert
    for (int off = 1; off < 256; off <<= 1) {
        int v[NEXP];
#pragma unroll
        for (int e = 0; e < NEXP; ++e) v[e] = (t >= off) ? hist[e][t - off] : 0;
        __syncthreads();
#pragma unroll
        for (int e = 0; e < NEXP; ++e) hist[e][t] += v[e];
        __syncthreads();
    }
    if (t == 0) {
        int s = 0;
        for (int e = 0; e < NEXP; ++e) { start_s[e] = s; s += hist[e][255]; }
    }
    __syncthreads();
    int run[NEXP];
#pragma unroll
    for (int e = 0; e < NEXP; ++e) run[e] = (t > 0) ? hist[e][t - 1] : 0;
    for (int i = 0; i < TPT; ++i) {
        const int n = base + i;
        const int e = le[i];
        const int pos = run[e]++;                 // stable rank within expert
        sort_idx[start_s[e] + pos] = n;           // full argsort (incl. overflow)
        if (pos < CAP) slot_to_token[e * CAP + pos] = n;
    }
    __syncthreads();
    // scale[n] = eprob[sort_idx[n]]  (the reference's unsorted-out * sorted-prob quirk)
    for (int n = t; n < N_TOK; n += 256) scale[n] = eprob[sort_idx[n]];
    if (t == 0) {
        float s = 0.f;
        for (int e = 0; e < NEXP; ++e) {
            const float f = (float)hist[e][255] / (float)N_TOK;
            const float p = p_sum[e] / (float)N_TOK;
            s += f * p;
        }
        aux_out[0] = 0.01f * (float)NEXP * s + 0.001f * (z_sum[0] / (float)N_TOK);
    }
}

// ---------------- gather tokens into per-expert capacity buffer ----------------
__global__ __launch_bounds__(256) void gather_kernel(
    const float* __restrict__ x, const int* __restrict__ slot_to_token,
    float* __restrict__ Xbuf)
{
    const int slot = blockIdx.x;
    const int tok = slot_to_token[slot];
    const int c = threadIdx.x * 4;
    float4 v = make_float4(0.f, 0.f, 0.f, 0.f);
    if (tok >= 0) v = *(const float4*)(x + (size_t)tok * DIM + c);
    *(float4*)(Xbuf + (size_t)slot * DIM + c) = v;
}

// ---------------- grouped GEMM 1: H = gelu(X @ W1 + b1) ----------------
#define BT 64
#define BK 16
__global__ __launch_bounds__(256) void gemm1_kernel(
    const float* __restrict__ Xbuf, const float* __restrict__ W1,
    const float* __restrict__ b1, float* __restrict__ Hbuf)
{
    const int tm = blockIdx.x;           // 0..127 (row tile over all experts)
    const int tn = blockIdx.y;           // 0..63
    const int e  = tm >> 4;              // 1024/64 = 16 row-tiles per expert
    const float* A = Xbuf + (size_t)tm * BT * DIM;
    const float* B = W1 + (size_t)e * DIM * HID + (size_t)tn * BT;
    __shared__ float As[BK][BT];
    __shared__ float Bs[BK][BT];
    const int tid = threadIdx.x;
    const int tx = tid & 15, ty = tid >> 4;
    float acc[4][4];
#pragma unroll
    for (int i = 0; i < 4; ++i)
#pragma unroll
        for (int j = 0; j < 4; ++j) acc[i][j] = 0.f;

    const int arow = tid >> 2, acg = tid & 3;
    const int bk = tid >> 4, bcg = tid & 15;
    for (int k0 = 0; k0 < DIM; k0 += BK) {
        const float4 av = *(const float4*)(A + (size_t)arow * DIM + k0 + acg * 4);
        const float4 bv = *(const float4*)(B + (size_t)(k0 + bk) * HID + bcg * 4);
        As[acg * 4 + 0][arow] = av.x;
        As[acg * 4 + 1][arow] = av.y;
        As[acg * 4 + 2][arow] = av.z;
        As[acg * 4 + 3][arow] = av.w;
        *(float4*)&Bs[bk][bcg * 4] = bv;
        __syncthreads();
#pragma unroll
        for (int k = 0; k < BK; ++k) {
            float a[4], b[4];
            *(float4*)a = *(const float4*)&As[k][ty * 4];
            *(float4*)b = *(const float4*)&Bs[k][tx * 4];
#pragma unroll
            for (int i = 0; i < 4; ++i)
#pragma unroll
                for (int j = 0; j < 4; ++j) acc[i][j] += a[i] * b[j];
        }
        __syncthreads();
    }
    const float4 bias = *(const float4*)(b1 + (size_t)e * HID + (size_t)tn * BT + tx * 4);
#pragma unroll
    for (int i = 0; i < 4; ++i) {
        const int r = tm * BT + ty * 4 + i;
        float4 v;
        v.x = gelu_exact(acc[i][0] + bias.x);
        v.y = gelu_exact(acc[i][1] + bias.y);
        v.z = gelu_exact(acc[i][2] + bias.z);
        v.w = gelu_exact(acc[i][3] + bias.w);
        *(float4*)(Hbuf + (size_t)r * HID + (size_t)tn * BT + tx * 4) = v;
    }
}

// ---------------- grouped GEMM 2: out = (H @ W2 + b2) * scale, scattered ----------------
__global__ __launch_bounds__(256) void gemm2_kernel(
    const float* __restrict__ Hbuf, const float* __restrict__ W2,
    const float* __restrict__ b2, const int* __restrict__ slot_to_token,
    const float* __restrict__ scale, float* __restrict__ out)
{
    const int tm = blockIdx.x;           // 0..127
    const int tn = blockIdx.y;           // 0..15
    const int e  = tm >> 4;
    const float* A = Hbuf + (size_t)tm * BT * HID;
    const float* B = W2 + (size_t)e * HID * DIM + (size_t)tn * BT;
    __shared__ float As[BK][BT];
    __shared__ float Bs[BK][BT];
    const int tid = threadIdx.x;
    const int tx = tid & 15, ty = tid >> 4;
    float acc[4][4];
#pragma unroll
    for (int i = 0; i < 4; ++i)
#pragma unroll
        for (int j = 0; j < 4; ++j) acc[i][j] = 0.f;

    const int arow = tid >> 2, acg = tid & 3;
    const int bk = tid >> 4, bcg = tid & 15;
    for (int k0 = 0; k0 < HID; k0 += BK) {
        const float4 av = *(const float4*)(A + (size_t)arow * HID + k0 + acg * 4);
        const float4 bv = *(const float4*)(B + (size_t)(k0 + bk) * DIM + bcg * 4);
        As[acg * 4 + 0][arow] = av.x;
        As[acg * 4 + 1][arow] = av.y;
        As[acg * 4 + 2][arow] = av.z;
        As[acg * 4 + 3][arow] = av.w;
        *(float4*)&Bs[bk][bcg * 4] = bv;
        __syncthreads();
#pragma unroll
        for (int k = 0; k < BK; ++k) {
            float a[4], b[4];
            *(float4*)a = *(const float4*)&As[k][ty * 4];
            *(float4*)b = *(const float4*)&Bs[k][tx * 4];
#pragma unroll
            for (int i = 0; i < 4; ++i)
#pragma unroll
                for (int j = 0; j < 4; ++j) acc[i][j] += a[i] * b[j];
        }
        __syncthreads();
    }
    const float4 bias = *(const float4*)(b2 + (size_t)e * DIM + (size_t)tn * BT + tx * 4);
#pragma unroll
    for (int i = 0; i < 4; ++i) {
        const int slot = tm * BT + ty * 4 + i;
        const int tok = slot_to_token[slot];
        if (tok >= 0) {
            const float s = scale[tok];
            float4 v;
            v.x = (acc[i][0] + bias.x) * s;
            v.y = (acc[i][1] + bias.y) * s;
            v.z = (acc[i][2] + bias.z) * s;
            v.w = (acc[i][3] + bias.w) * s;
            *(float4*)(out + (size_t)tok * DIM + (size_t)tn * BT + tx * 4) = v;
        }
    }
}

extern "C" void kernel_launch(void* const* d_in, const int* in_sizes, int n_in,
                              void* d_out, int out_size, void* d_ws, size_t ws_size,
                              hipStream_t stream)
{
    const float* x  = (const float*)d_in[0];
    const float* Wg = (const float*)d_in[1];
    const float* W1 = (const float*)d_in[2];
    const float* b1 = (const float*)d_in[3];
    const float* W2 = (const float*)d_in[4];
    const float* b2 = (const float*)d_in[5];
    float* out = (float*)d_out;

    // workspace layout (160.2 MB total)
    float* Xbuf  = (float*)d_ws;                          // 8192*1024 f32 = 32 MB
    float* Hbuf  = Xbuf + (size_t)N_TOK * DIM;            // 8192*4096 f32 = 128 MB
    int*   ei    = (int*)(Hbuf + (size_t)N_TOK * HID);    // 8192 i32
    float* eprob = (float*)(ei + N_TOK);                  // 8192 f32
    int*   sort_idx = (int*)(eprob + N_TOK);              // 8192 i32
    float* scale = (float*)(sort_idx + N_TOK);            // 8192 f32
    int*   s2t   = (int*)(scale + N_TOK);                 // 8192 i32
    float* p_sum = (float*)(s2t + NEXP * CAP);            // 8 f32
    float* z_sum = p_sum + NEXP;                          // 1 f32

    hipMemsetAsync(p_sum, 0, (NEXP + 1) * sizeof(float), stream);
    hipMemsetAsync(s2t, 0xFF, (size_t)NEXP * CAP * sizeof(int), stream);  // -1
    hipMemsetAsync(out, 0, (size_t)N_TOK * DIM * sizeof(float), stream);  // dropped tokens -> 0

    router_kernel<<<N_TOK, 64, 0, stream>>>(x, Wg, ei, eprob, p_sum, z_sum);
    dispatch_kernel<<<1, 256, 0, stream>>>(ei, eprob, s2t, sort_idx, scale,
                                           p_sum, z_sum, out + (size_t)N_TOK * DIM);
    gather_kernel<<<NEXP * CAP, 256, 0, stream>>>(x, s2t, Xbuf);
    gemm1_kernel<<<dim3(128, 64), 256, 0, stream>>>(Xbuf, W1, b1, Hbuf);
    gemm2_kernel<<<dim3(128, 16), 256, 0, stream>>>(Hbuf, W2, b2, s2t, scale, out);
}

// Round 2
// 1537.606 us; speedup vs baseline: 2.0198x; 2.0198x over previous
//
#include <hip/hip_runtime.h>
#include <math.h>

#define N_TOK 8192
#define DIM   1024
#define NEXP  8
#define HID   4096
#define CAP   1024
#define TPT   (N_TOK / 256)

typedef _Float16 f16x8 __attribute__((ext_vector_type(8)));
typedef _Float16 f16x4 __attribute__((ext_vector_type(4)));
typedef float    f32x4 __attribute__((ext_vector_type(4)));

__device__ __forceinline__ float gelu_exact(float v) {
    return 0.5f * v * (1.0f + erff(v * 0.7071067811865476f));
}

// async 16B global -> LDS (wave-uniform base + lane*16 semantics)
__device__ __forceinline__ void gl_lds16(const void* g, void* l) {
    __builtin_amdgcn_global_load_lds(
        (const __attribute__((address_space(1))) unsigned int*)g,
        (__attribute__((address_space(3))) unsigned int*)l, 16, 0, 0);
}

// ---------------- router ----------------
__global__ __launch_bounds__(64) void router_kernel(
    const float* __restrict__ x, const float* __restrict__ Wg,
    int* __restrict__ ei, float* __restrict__ eprob,
    float* __restrict__ p_sum, float* __restrict__ z_sum)
{
    const int t = blockIdx.x;
    const int lane = threadIdx.x;
    const float* xr = x + (size_t)t * DIM;
    float acc[NEXP];
#pragma unroll
    for (int e = 0; e < NEXP; ++e) acc[e] = 0.f;
#pragma unroll
    for (int k = 0; k < DIM / 64; ++k) {
        const int d = k * 64 + lane;
        const float xv = xr[d];
        const float4 w0 = *(const float4*)(Wg + (size_t)d * NEXP);
        const float4 w1 = *(const float4*)(Wg + (size_t)d * NEXP + 4);
        acc[0] += xv * w0.x; acc[1] += xv * w0.y;
        acc[2] += xv * w0.z; acc[3] += xv * w0.w;
        acc[4] += xv * w1.x; acc[5] += xv * w1.y;
        acc[6] += xv * w1.z; acc[7] += xv * w1.w;
    }
#pragma unroll
    for (int off = 32; off > 0; off >>= 1) {
#pragma unroll
        for (int e = 0; e < NEXP; ++e)
            acc[e] += __shfl_down(acc[e], off, 64);
    }
    if (lane == 0) {
        float m = acc[0]; int arg = 0;
#pragma unroll
        for (int e = 1; e < NEXP; ++e) { if (acc[e] > m) { m = acc[e]; arg = e; } }
        float ex[NEXP]; float se = 0.f;
#pragma unroll
        for (int e = 0; e < NEXP; ++e) { ex[e] = expf(acc[e] - m); se += ex[e]; }
        const float lse = m + logf(se);
        const float inv = 1.f / se;
#pragma unroll
        for (int e = 0; e < NEXP; ++e) atomicAdd(&p_sum[e], ex[e] * inv);
        atomicAdd(z_sum, lse * lse);
        ei[t] = arg;
        eprob[t] = ex[arg] * inv;
    }
}

// ---------------- dispatch ----------------
__global__ __launch_bounds__(256) void dispatch_kernel(
    const int* __restrict__ ei, const float* __restrict__ eprob,
    int* __restrict__ slot_to_token, int* __restrict__ sort_idx,
    float* __restrict__ scale,
    const float* __restrict__ p_sum, const float* __restrict__ z_sum,
    float* __restrict__ aux_out)
{
    __shared__ int hist[NEXP][256];
    __shared__ int start_s[NEXP];
    const int t = threadIdx.x;
    int le[TPT];
    int lh[NEXP];
#pragma unroll
    for (int e = 0; e < NEXP; ++e) lh[e] = 0;
    const int base = t * TPT;
    for (int i = 0; i < TPT; ++i) {
        const int e = ei[base + i];
        le[i] = e;
        lh[e]++;
    }
#pragma unroll
    for (int e = 0; e < NEXP; ++e) hist[e][t] = lh[e];
    __syncthreads();
    for (int off = 1; off < 256; off <<= 1) {
        int v[NEXP];
#pragma unroll
        for (int e = 0; e < NEXP; ++e) v[e] = (t >= off) ? hist[e][t - off] : 0;
        __syncthreads();
#pragma unroll
        for (int e = 0; e < NEXP; ++e) hist[e][t] += v[e];
        __syncthreads();
    }
    if (t == 0) {
        int s = 0;
        for (int e = 0; e < NEXP; ++e) { start_s[e] = s; s += hist[e][255]; }
    }
    __syncthreads();
    int run[NEXP];
#pragma unroll
    for (int e = 0; e < NEXP; ++e) run[e] = (t > 0) ? hist[e][t - 1] : 0;
    for (int i = 0; i < TPT; ++i) {
        const int n = base + i;
        const int e = le[i];
        const int pos = run[e]++;
        sort_idx[start_s[e] + pos] = n;
        if (pos < CAP) slot_to_token[e * CAP + pos] = n;
    }
    __syncthreads();
    for (int n = t; n < N_TOK; n += 256) scale[n] = eprob[sort_idx[n]];
    if (t == 0) {
        float s = 0.f;
        for (int e = 0; e < NEXP; ++e) {
            const float f = (float)hist[e][255] / (float)N_TOK;
            const float p = p_sum[e] / (float)N_TOK;
            s += f * p;
        }
        aux_out[0] = 0.01f * (float)NEXP * s + 0.001f * (z_sum[0] / (float)N_TOK);
    }
}

// ---------------- gather tokens into per-expert fp16 buffer ----------------
__global__ __launch_bounds__(256) void gather_kernel(
    const float* __restrict__ x, const int* __restrict__ slot_to_token,
    _Float16* __restrict__ Xbuf)
{
    const int slot = blockIdx.x;
    const int tok = slot_to_token[slot];
    const int c = threadIdx.x * 4;
    float4 v = make_float4(0.f, 0.f, 0.f, 0.f);
    if (tok >= 0) v = *(const float4*)(x + (size_t)tok * DIM + c);
    f16x4 o;
    o[0] = (_Float16)v.x; o[1] = (_Float16)v.y;
    o[2] = (_Float16)v.z; o[3] = (_Float16)v.w;
    *(f16x4*)(Xbuf + (size_t)slot * DIM + c) = o;
}

// ---------------- fp32 [E][R][C] -> fp16 [E][C][R] transpose ----------------
template<int R, int C>
__global__ __launch_bounds__(256) void transpose_f32_f16(
    const float* __restrict__ in, _Float16* __restrict__ outT)
{
    const int e = blockIdx.z;
    const int r0 = blockIdx.y * 64, c0 = blockIdx.x * 64;
    const float* pin = in + (size_t)e * R * C;
    _Float16* pot = outT + (size_t)e * R * C;
    __shared__ _Float16 tile[64][72];
    const int tid = threadIdx.x;
    const int rr = tid >> 4, cc = (tid & 15) * 4;
#pragma unroll
    for (int ri = 0; ri < 4; ++ri) {
        const int row = rr + ri * 16;
        const float4 v = *(const float4*)&pin[(size_t)(r0 + row) * C + c0 + cc];
        tile[cc + 0][row] = (_Float16)v.x;
        tile[cc + 1][row] = (_Float16)v.y;
        tile[cc + 2][row] = (_Float16)v.z;
        tile[cc + 3][row] = (_Float16)v.w;
    }
    __syncthreads();
    const int c = tid >> 2, rs = (tid & 3) * 16;
    const f16x8 o0 = *(const f16x8*)&tile[c][rs];
    const f16x8 o1 = *(const f16x8*)&tile[c][rs + 8];
    _Float16* po = &pot[(size_t)(c0 + c) * R + r0 + rs];
    *(f16x8*)po = o0;
    *(f16x8*)(po + 8) = o1;
}

// ---------------- MFMA GEMM 1: Hbuf = gelu(Xbuf @ W1 + b1), fp16 ----------------
// A: Xbuf [8192][1024] fp16 row-major. Bt: W1t [E][HID][DIM] fp16 (n-major).
__global__ __launch_bounds__(256) void gemm1_kernel(
    const _Float16* __restrict__ A, const _Float16* __restrict__ Bt,
    const float* __restrict__ b1, _Float16* __restrict__ Hbuf)
{
    const int mb = blockIdx.x;               // 0..63 (128 rows each)
    const int nb = blockIdx.y;               // 0..31
    const int e  = mb >> 3;                  // 1024 rows / 128 = 8 m-blocks per expert
    const _Float16* Ab = A  + (size_t)mb * 128 * DIM;
    const _Float16* Bb = Bt + (size_t)e * HID * DIM + (size_t)nb * 128 * DIM;
    __shared__ _Float16 As[128 * 32];
    __shared__ _Float16 Bs[128 * 32];
    const int tid = threadIdx.x;
    const int lane = tid & 63, w = tid >> 6;
    const int wm = (w >> 1) * 64, wn = (w & 1) * 64;
    const int lr = lane & 15, quad = lane >> 4;

    f32x4 acc[4][4];
#pragma unroll
    for (int i = 0; i < 4; ++i)
#pragma unroll
        for (int j = 0; j < 4; ++j) acc[i][j] = (f32x4)0.f;

    for (int k0 = 0; k0 < DIM; k0 += 32) {
#pragma unroll
        for (int i = 0; i < 2; ++i) {
            const int idx = i * 256 + tid;   // 0..511: row=idx>>2, seg=idx&3
            const int row = idx >> 2, seg = idx & 3;
            gl_lds16(Ab + (size_t)row * DIM + k0 + seg * 8, &As[idx * 8]);
            gl_lds16(Bb + (size_t)row * DIM + k0 + seg * 8, &Bs[idx * 8]);
        }
        __syncthreads();
        f16x8 af[4], bf[4];
#pragma unroll
        for (int i = 0; i < 4; ++i)
            af[i] = *(const f16x8*)&As[(wm + i * 16 + lr) * 32 + quad * 8];
#pragma unroll
        for (int j = 0; j < 4; ++j)
            bf[j] = *(const f16x8*)&Bs[(wn + j * 16 + lr) * 32 + quad * 8];
#pragma unroll
        for (int i = 0; i < 4; ++i)
#pragma unroll
            for (int j = 0; j < 4; ++j)
                acc[i][j] = __builtin_amdgcn_mfma_f32_16x16x32_f16(af[i], bf[j], acc[i][j], 0, 0, 0);
        __syncthreads();
    }
    // epilogue: bias + gelu, fp16 store (C/D: col=lane&15, row=quad*4+reg)
    float bias[4];
#pragma unroll
    for (int j = 0; j < 4; ++j)
        bias[j] = b1[(size_t)e * HID + (size_t)nb * 128 + wn + j * 16 + lr];
#pragma unroll
    for (int i = 0; i < 4; ++i) {
#pragma unroll
        for (int r = 0; r < 4; ++r) {
            const size_t row = (size_t)mb * 128 + wm + i * 16 + quad * 4 + r;
            _Float16* hr = Hbuf + row * HID + (size_t)nb * 128;
#pragma unroll
            for (int j = 0; j < 4; ++j)
                hr[wn + j * 16 + lr] = (_Float16)gelu_exact(acc[i][j][r] + bias[j]);
        }
    }
}

// ---------------- MFMA GEMM 2: out[tok] = (Hbuf @ W2 + b2) * scale ----------------
// A: Hbuf [8192][4096] fp16. Bt: W2t [E][DIM][HID] fp16 (n-major).
__global__ __launch_bounds__(256) void gemm2_kernel(
    const _Float16* __restrict__ A, const _Float16* __restrict__ Bt,
    const float* __restrict__ b2, const int* __restrict__ slot_to_token,
    const float* __restrict__ scale, float* __restrict__ out)
{
    const int mb = blockIdx.x;               // 0..63
    const int nb = blockIdx.y;               // 0..7
    const int e  = mb >> 3;
    const _Float16* Ab = A  + (size_t)mb * 128 * HID;
    const _Float16* Bb = Bt + (size_t)e * DIM * HID + (size_t)nb * 128 * HID;
    __shared__ _Float16 As[128 * 32];
    __shared__ _Float16 Bs[128 * 32];
    const int tid = threadIdx.x;
    const int lane = tid & 63, w = tid >> 6;
    const int wm = (w >> 1) * 64, wn = (w & 1) * 64;
    const int lr = lane & 15, quad = lane >> 4;

    f32x4 acc[4][4];
#pragma unroll
    for (int i = 0; i < 4; ++i)
#pragma unroll
        for (int j = 0; j < 4; ++j) acc[i][j] = (f32x4)0.f;

    for (int k0 = 0; k0 < HID; k0 += 32) {
#pragma unroll
        for (int i = 0; i < 2; ++i) {
            const int idx = i * 256 + tid;
            const int row = idx >> 2, seg = idx & 3;
            gl_lds16(Ab + (size_t)row * HID + k0 + seg * 8, &As[idx * 8]);
            gl_lds16(Bb + (size_t)row * HID + k0 + seg * 8, &Bs[idx * 8]);
        }
        __syncthreads();
        f16x8 af[4], bf[4];
#pragma unroll
        for (int i = 0; i < 4; ++i)
            af[i] = *(const f16x8*)&As[(wm + i * 16 + lr) * 32 + quad * 8];
#pragma unroll
        for (int j = 0; j < 4; ++j)
            bf[j] = *(const f16x8*)&Bs[(wn + j * 16 + lr) * 32 + quad * 8];
#pragma unroll
        for (int i = 0; i < 4; ++i)
#pragma unroll
            for (int j = 0; j < 4; ++j)
                acc[i][j] = __builtin_amdgcn_mfma_f32_16x16x32_f16(af[i], bf[j], acc[i][j], 0, 0, 0);
        __syncthreads();
    }
    float bias[4];
#pragma unroll
    for (int j = 0; j < 4; ++j)
        bias[j] = b2[(size_t)e * DIM + (size_t)nb * 128 + wn + j * 16 + lr];
#pragma unroll
    for (int i = 0; i < 4; ++i) {
#pragma unroll
        for (int r = 0; r < 4; ++r) {
            const int slot = mb * 128 + wm + i * 16 + quad * 4 + r;
            const int tok = slot_to_token[slot];
            if (tok >= 0) {
                const float sc = scale[tok];
                float* orow = out + (size_t)tok * DIM + (size_t)nb * 128;
#pragma unroll
                for (int j = 0; j < 4; ++j)
                    orow[wn + j * 16 + lr] = (acc[i][j][r] + bias[j]) * sc;
            }
        }
    }
}

extern "C" void kernel_launch(void* const* d_in, const int* in_sizes, int n_in,
                              void* d_out, int out_size, void* d_ws, size_t ws_size,
                              hipStream_t stream)
{
    const float* x  = (const float*)d_in[0];
    const float* Wg = (const float*)d_in[1];
    const float* W1 = (const float*)d_in[2];
    const float* b1 = (const float*)d_in[3];
    const float* W2 = (const float*)d_in[4];
    const float* b2 = (const float*)d_in[5];
    float* out = (float*)d_out;

    // workspace layout (~144.2 MB; proven ws >= 160.2 MB from round 1)
    _Float16* Wt   = (_Float16*)d_ws;                         // 8*4096*1024 fp16 = 64 MB (W1t, later reused as W2t)
    _Float16* Xbuf = Wt + (size_t)NEXP * HID * DIM;           // 8192*1024 fp16 = 16 MB
    _Float16* Hbuf = Xbuf + (size_t)N_TOK * DIM;              // 8192*4096 fp16 = 64 MB
    int*   ei    = (int*)(Hbuf + (size_t)N_TOK * HID);
    float* eprob = (float*)(ei + N_TOK);
    int*   sort_idx = (int*)(eprob + N_TOK);
    float* scale = (float*)(sort_idx + N_TOK);
    int*   s2t   = (int*)(scale + N_TOK);
    float* p_sum = (float*)(s2t + NEXP * CAP);
    float* z_sum = p_sum + NEXP;

    hipMemsetAsync(p_sum, 0, (NEXP + 1) * sizeof(float), stream);
    hipMemsetAsync(s2t, 0xFF, (size_t)NEXP * CAP * sizeof(int), stream);
    hipMemsetAsync(out, 0, (size_t)N_TOK * DIM * sizeof(float), stream);

    // W1 [E][D][H] -> W1t [E][H][D] fp16
    transpose_f32_f16<DIM, HID><<<dim3(HID / 64, DIM / 64, NEXP), 256, 0, stream>>>(W1, Wt);
    router_kernel<<<N_TOK, 64, 0, stream>>>(x, Wg, ei, eprob, p_sum, z_sum);
    dispatch_kernel<<<1, 256, 0, stream>>>(ei, eprob, s2t, sort_idx, scale,
                                           p_sum, z_sum, out + (size_t)N_TOK * DIM);
    gather_kernel<<<NEXP * CAP, 256, 0, stream>>>(x, s2t, Xbuf);
    gemm1_kernel<<<dim3(64, 32), 256, 0, stream>>>(Xbuf, Wt, b1, Hbuf);
    // W2 [E][H][D] -> W2t [E][D][H] fp16 (reuses W1t region; stream-ordered after gemm1)
    transpose_f32_f16<HID, DIM><<<dim3(DIM / 64, HID / 64, NEXP), 256, 0, stream>>>(W2, Wt);
    gemm2_kernel<<<dim3(64, 8), 256, 0, stream>>>(Hbuf, Wt, b2, s2t, scale, out);
}

// Round 3
// 614.050 us; speedup vs baseline: 5.0576x; 2.5040x over previous
//
#include <hip/hip_runtime.h>
#include <math.h>

#define N_TOK 8192
#define DIM   1024
#define NEXP  8
#define HID   4096
#define CAP   1024
#define TPT   (N_TOK / 256)
#define RT_BLOCKS 256
#define RT_TPB (N_TOK / RT_BLOCKS)   // 32 tokens per router block

typedef _Float16 f16x8 __attribute__((ext_vector_type(8)));
typedef _Float16 f16x4 __attribute__((ext_vector_type(4)));
typedef float    f32x4 __attribute__((ext_vector_type(4)));

__device__ __forceinline__ float gelu_exact(float v) {
    return 0.5f * v * (1.0f + erff(v * 0.7071067811865476f));
}

__device__ __forceinline__ void gl_lds16(const void* g, void* l) {
    __builtin_amdgcn_global_load_lds(
        (const __attribute__((address_space(1))) unsigned int*)g,
        (__attribute__((address_space(3))) unsigned int*)l, 16, 0, 0);
}

// ---------------- router: 256 blocks, per-block partial p/z sums, NO global atomics ----------------
__global__ __launch_bounds__(256) void router_kernel(
    const float* __restrict__ x, const float* __restrict__ Wg,
    int* __restrict__ ei, float* __restrict__ eprob,
    float* __restrict__ pp)            // [RT_BLOCKS][NEXP+1]
{
    __shared__ float psum_s[NEXP + 1];
    const int tid = threadIdx.x;
    const int w = tid >> 6, lane = tid & 63;
    if (tid <= NEXP) psum_s[tid] = 0.f;
    __syncthreads();

    float p_loc[NEXP];
#pragma unroll
    for (int e = 0; e < NEXP; ++e) p_loc[e] = 0.f;
    float z_loc = 0.f;

    for (int ti = 0; ti < RT_TPB / 4; ++ti) {          // 8 tokens per wave
        const int t = blockIdx.x * RT_TPB + w * (RT_TPB / 4) + ti;
        const float* xr = x + (size_t)t * DIM;
        float acc[NEXP];
#pragma unroll
        for (int e = 0; e < NEXP; ++e) acc[e] = 0.f;
#pragma unroll
        for (int k = 0; k < DIM / 64; ++k) {
            const int d = k * 64 + lane;
            const float xv = xr[d];
            const float4 w0 = *(const float4*)(Wg + (size_t)d * NEXP);
            const float4 w1 = *(const float4*)(Wg + (size_t)d * NEXP + 4);
            acc[0] += xv * w0.x; acc[1] += xv * w0.y;
            acc[2] += xv * w0.z; acc[3] += xv * w0.w;
            acc[4] += xv * w1.x; acc[5] += xv * w1.y;
            acc[6] += xv * w1.z; acc[7] += xv * w1.w;
        }
#pragma unroll
        for (int off = 32; off > 0; off >>= 1) {
#pragma unroll
            for (int e = 0; e < NEXP; ++e)
                acc[e] += __shfl_down(acc[e], off, 64);
        }
        if (lane == 0) {
            float m = acc[0]; int arg = 0;
#pragma unroll
            for (int e = 1; e < NEXP; ++e) { if (acc[e] > m) { m = acc[e]; arg = e; } }
            float ex[NEXP]; float se = 0.f;
#pragma unroll
            for (int e = 0; e < NEXP; ++e) { ex[e] = expf(acc[e] - m); se += ex[e]; }
            const float lse = m + logf(se);
            const float inv = 1.f / se;
#pragma unroll
            for (int e = 0; e < NEXP; ++e) p_loc[e] += ex[e] * inv;
            z_loc += lse * lse;
            ei[t] = arg;
            eprob[t] = ex[arg] * inv;
        }
    }
    if (lane == 0) {                    // 4 waves -> LDS atomics (cheap, per-block)
#pragma unroll
        for (int e = 0; e < NEXP; ++e) atomicAdd(&psum_s[e], p_loc[e]);
        atomicAdd(&psum_s[NEXP], z_loc);
    }
    __syncthreads();
    if (tid <= NEXP) pp[blockIdx.x * (NEXP + 1) + tid] = psum_s[tid];
}

// ---------------- dispatch: reduce pp, stable ranks, sort_idx, capacity, aux loss ----------------
__global__ __launch_bounds__(256) void dispatch_kernel(
    const int* __restrict__ ei, const float* __restrict__ eprob,
    int* __restrict__ slot_to_token, int* __restrict__ sort_idx,
    float* __restrict__ scale,
    const float* __restrict__ pp,      // [RT_BLOCKS][NEXP+1]
    float* __restrict__ aux_out)
{
    __shared__ int hist[NEXP][256];
    __shared__ int start_s[NEXP];
    __shared__ float red_s[4][NEXP + 1];
    __shared__ float tot_s[NEXP + 1];
    const int t = threadIdx.x;
    const int w = t >> 6, lane = t & 63;

    // ---- reduce per-block router partials (RT_BLOCKS == 256 == blockDim) ----
    {
        float v[NEXP + 1];
#pragma unroll
        for (int j = 0; j <= NEXP; ++j) v[j] = pp[t * (NEXP + 1) + j];
#pragma unroll
        for (int j = 0; j <= NEXP; ++j) {
            float s = v[j];
#pragma unroll
            for (int off = 32; off > 0; off >>= 1) s += __shfl_down(s, off, 64);
            if (lane == 0) red_s[w][j] = s;
        }
    }
    __syncthreads();
    if (t <= NEXP) tot_s[t] = red_s[0][t] + red_s[1][t] + red_s[2][t] + red_s[3][t];
    __syncthreads();

    int le[TPT];
    int lh[NEXP];
#pragma unroll
    for (int e = 0; e < NEXP; ++e) lh[e] = 0;
    const int base = t * TPT;
    for (int i = 0; i < TPT; ++i) {
        const int e = ei[base + i];
        le[i] = e;
        lh[e]++;
    }
#pragma unroll
    for (int e = 0; e < NEXP; ++e) hist[e][t] = lh[e];
    __syncthreads();
    for (int off = 1; off < 256; off <<= 1) {
        int v[NEXP];
#pragma unroll
        for (int e = 0; e < NEXP; ++e) v[e] = (t >= off) ? hist[e][t - off] : 0;
        __syncthreads();
#pragma unroll
        for (int e = 0; e < NEXP; ++e) hist[e][t] += v[e];
        __syncthreads();
    }
    if (t == 0) {
        int s = 0;
        for (int e = 0; e < NEXP; ++e) { start_s[e] = s; s += hist[e][255]; }
    }
    __syncthreads();
    int run[NEXP];
#pragma unroll
    for (int e = 0; e < NEXP; ++e) run[e] = (t > 0) ? hist[e][t - 1] : 0;
    for (int i = 0; i < TPT; ++i) {
        const int n = base + i;
        const int e = le[i];
        const int pos = run[e]++;
        sort_idx[start_s[e] + pos] = n;
        if (pos < CAP) slot_to_token[e * CAP + pos] = n;
    }
    __syncthreads();
    for (int n = t; n < N_TOK; n += 256) scale[n] = eprob[sort_idx[n]];
    if (t == 0) {
        float s = 0.f;
        for (int e = 0; e < NEXP; ++e) {
            const float f = (float)hist[e][255] / (float)N_TOK;
            const float p = tot_s[e] / (float)N_TOK;
            s += f * p;
        }
        aux_out[0] = 0.01f * (float)NEXP * s + 0.001f * (tot_s[NEXP] / (float)N_TOK);
    }
}

// ---------------- gather tokens into per-expert fp16 buffer ----------------
__global__ __launch_bounds__(256) void gather_kernel(
    const float* __restrict__ x, const int* __restrict__ slot_to_token,
    _Float16* __restrict__ Xbuf)
{
    const int slot = blockIdx.x;
    const int tok = slot_to_token[slot];
    const int c = threadIdx.x * 4;
    float4 v = make_float4(0.f, 0.f, 0.f, 0.f);
    if (tok >= 0) v = *(const float4*)(x + (size_t)tok * DIM + c);
    f16x4 o;
    o[0] = (_Float16)v.x; o[1] = (_Float16)v.y;
    o[2] = (_Float16)v.z; o[3] = (_Float16)v.w;
    *(f16x4*)(Xbuf + (size_t)slot * DIM + c) = o;
}

// ---------------- fp32 [E][R][C] -> fp16 [E][C][R] transpose ----------------
template<int R, int C>
__global__ __launch_bounds__(256) void transpose_f32_f16(
    const float* __restrict__ in, _Float16* __restrict__ outT)
{
    const int e = blockIdx.z;
    const int r0 = blockIdx.y * 64, c0 = blockIdx.x * 64;
    const float* pin = in + (size_t)e * R * C;
    _Float16* pot = outT + (size_t)e * R * C;
    __shared__ _Float16 tile[64][72];
    const int tid = threadIdx.x;
    const int rr = tid >> 4, cc = (tid & 15) * 4;
#pragma unroll
    for (int ri = 0; ri < 4; ++ri) {
        const int row = rr + ri * 16;
        const float4 v = *(const float4*)&pin[(size_t)(r0 + row) * C + c0 + cc];
        tile[cc + 0][row] = (_Float16)v.x;
        tile[cc + 1][row] = (_Float16)v.y;
        tile[cc + 2][row] = (_Float16)v.z;
        tile[cc + 3][row] = (_Float16)v.w;
    }
    __syncthreads();
    const int c = tid >> 2, rs = (tid & 3) * 16;
    const f16x8 o0 = *(const f16x8*)&tile[c][rs];
    const f16x8 o1 = *(const f16x8*)&tile[c][rs + 8];
    _Float16* po = &pot[(size_t)(c0 + c) * R + r0 + rs];
    *(f16x8*)po = o0;
    *(f16x8*)(po + 8) = o1;
}

// ---------------- MFMA GEMM 1: Hbuf = gelu(Xbuf @ W1 + b1), fp16 ----------------
__global__ __launch_bounds__(256) void gemm1_kernel(
    const _Float16* __restrict__ A, const _Float16* __restrict__ Bt,
    const float* __restrict__ b1, _Float16* __restrict__ Hbuf)
{
    const int mb = blockIdx.x;
    const int nb = blockIdx.y;
    const int e  = mb >> 3;
    const _Float16* Ab = A  + (size_t)mb * 128 * DIM;
    const _Float16* Bb = Bt + (size_t)e * HID * DIM + (size_t)nb * 128 * DIM;
    __shared__ _Float16 As[128 * 32];
    __shared__ _Float16 Bs[128 * 32];
    const int tid = threadIdx.x;
    const int lane = tid & 63, w = tid >> 6;
    const int wm = (w >> 1) * 64, wn = (w & 1) * 64;
    const int lr = lane & 15, quad = lane >> 4;

    f32x4 acc[4][4];
#pragma unroll
    for (int i = 0; i < 4; ++i)
#pragma unroll
        for (int j = 0; j < 4; ++j) acc[i][j] = (f32x4)0.f;

    for (int k0 = 0; k0 < DIM; k0 += 32) {
#pragma unroll
        for (int i = 0; i < 2; ++i) {
            const int idx = i * 256 + tid;
            const int row = idx >> 2, seg = idx & 3;
            gl_lds16(Ab + (size_t)row * DIM + k0 + seg * 8, &As[idx * 8]);
            gl_lds16(Bb + (size_t)row * DIM + k0 + seg * 8, &Bs[idx * 8]);
        }
        __syncthreads();
        f16x8 af[4], bf[4];
#pragma unroll
        for (int i = 0; i < 4; ++i)
            af[i] = *(const f16x8*)&As[(wm + i * 16 + lr) * 32 + quad * 8];
#pragma unroll
        for (int j = 0; j < 4; ++j)
            bf[j] = *(const f16x8*)&Bs[(wn + j * 16 + lr) * 32 + quad * 8];
#pragma unroll
        for (int i = 0; i < 4; ++i)
#pragma unroll
            for (int j = 0; j < 4; ++j)
                acc[i][j] = __builtin_amdgcn_mfma_f32_16x16x32_f16(af[i], bf[j], acc[i][j], 0, 0, 0);
        __syncthreads();
    }
    float bias[4];
#pragma unroll
    for (int j = 0; j < 4; ++j)
        bias[j] = b1[(size_t)e * HID + (size_t)nb * 128 + wn + j * 16 + lr];
#pragma unroll
    for (int i = 0; i < 4; ++i) {
#pragma unroll
        for (int r = 0; r < 4; ++r) {
            const size_t row = (size_t)mb * 128 + wm + i * 16 + quad * 4 + r;
            _Float16* hr = Hbuf + row * HID + (size_t)nb * 128;
#pragma unroll
            for (int j = 0; j < 4; ++j)
                hr[wn + j * 16 + lr] = (_Float16)gelu_exact(acc[i][j][r] + bias[j]);
        }
    }
}

// ---------------- MFMA GEMM 2: out[tok] = (Hbuf @ W2 + b2) * scale ----------------
__global__ __launch_bounds__(256) void gemm2_kernel(
    const _Float16* __restrict__ A, const _Float16* __restrict__ Bt,
    const float* __restrict__ b2, const int* __restrict__ slot_to_token,
    const float* __restrict__ scale, float* __restrict__ out)
{
    const int mb = blockIdx.x;
    const int nb = blockIdx.y;
    const int e  = mb >> 3;
    const _Float16* Ab = A  + (size_t)mb * 128 * HID;
    const _Float16* Bb = Bt + (size_t)e * DIM * HID + (size_t)nb * 128 * HID;
    __shared__ _Float16 As[128 * 32];
    __shared__ _Float16 Bs[128 * 32];
    const int tid = threadIdx.x;
    const int lane = tid & 63, w = tid >> 6;
    const int wm = (w >> 1) * 64, wn = (w & 1) * 64;
    const int lr = lane & 15, quad = lane >> 4;

    f32x4 acc[4][4];
#pragma unroll
    for (int i = 0; i < 4; ++i)
#pragma unroll
        for (int j = 0; j < 4; ++j) acc[i][j] = (f32x4)0.f;

    for (int k0 = 0; k0 < HID; k0 += 32) {
#pragma unroll
        for (int i = 0; i < 2; ++i) {
            const int idx = i * 256 + tid;
            const int row = idx >> 2, seg = idx & 3;
            gl_lds16(Ab + (size_t)row * HID + k0 + seg * 8, &As[idx * 8]);
            gl_lds16(Bb + (size_t)row * HID + k0 + seg * 8, &Bs[idx * 8]);
        }
        __syncthreads();
        f16x8 af[4], bf[4];
#pragma unroll
        for (int i = 0; i < 4; ++i)
            af[i] = *(const f16x8*)&As[(wm + i * 16 + lr) * 32 + quad * 8];
#pragma unroll
        for (int j = 0; j < 4; ++j)
            bf[j] = *(const f16x8*)&Bs[(wn + j * 16 + lr) * 32 + quad * 8];
#pragma unroll
        for (int i = 0; i < 4; ++i)
#pragma unroll
            for (int j = 0; j < 4; ++j)
                acc[i][j] = __builtin_amdgcn_mfma_f32_16x16x32_f16(af[i], bf[j], acc[i][j], 0, 0, 0);
        __syncthreads();
    }
    float bias[4];
#pragma unroll
    for (int j = 0; j < 4; ++j)
        bias[j] = b2[(size_t)e * DIM + (size_t)nb * 128 + wn + j * 16 + lr];
#pragma unroll
    for (int i = 0; i < 4; ++i) {
#pragma unroll
        for (int r = 0; r < 4; ++r) {
            const int slot = mb * 128 + wm + i * 16 + quad * 4 + r;
            const int tok = slot_to_token[slot];
            if (tok >= 0) {
                const float sc = scale[tok];
                float* orow = out + (size_t)tok * DIM + (size_t)nb * 128;
#pragma unroll
                for (int j = 0; j < 4; ++j)
                    orow[wn + j * 16 + lr] = (acc[i][j][r] + bias[j]) * sc;
            }
        }
    }
}

extern "C" void kernel_launch(void* const* d_in, const int* in_sizes, int n_in,
                              void* d_out, int out_size, void* d_ws, size_t ws_size,
                              hipStream_t stream)
{
    const float* x  = (const float*)d_in[0];
    const float* Wg = (const float*)d_in[1];
    const float* W1 = (const float*)d_in[2];
    const float* b1 = (const float*)d_in[3];
    const float* W2 = (const float*)d_in[4];
    const float* b2 = (const float*)d_in[5];
    float* out = (float*)d_out;

    _Float16* Wt   = (_Float16*)d_ws;                         // 64 MB (W1t, later W2t)
    _Float16* Xbuf = Wt + (size_t)NEXP * HID * DIM;           // 16 MB
    _Float16* Hbuf = Xbuf + (size_t)N_TOK * DIM;              // 64 MB
    int*   ei    = (int*)(Hbuf + (size_t)N_TOK * HID);
    float* eprob = (float*)(ei + N_TOK);
    int*   sort_idx = (int*)(eprob + N_TOK);
    float* scale = (float*)(sort_idx + N_TOK);
    int*   s2t   = (int*)(scale + N_TOK);
    float* pp    = (float*)(s2t + NEXP * CAP);                // [256][9]

    hipMemsetAsync(s2t, 0xFF, (size_t)NEXP * CAP * sizeof(int), stream);
    hipMemsetAsync(out, 0, (size_t)N_TOK * DIM * sizeof(float), stream);

    transpose_f32_f16<DIM, HID><<<dim3(HID / 64, DIM / 64, NEXP), 256, 0, stream>>>(W1, Wt);
    router_kernel<<<RT_BLOCKS, 256, 0, stream>>>(x, Wg, ei, eprob, pp);
    dispatch_kernel<<<1, 256, 0, stream>>>(ei, eprob, s2t, sort_idx, scale,
                                           pp, out + (size_t)N_TOK * DIM);
    gather_kernel<<<NEXP * CAP, 256, 0, stream>>>(x, s2t, Xbuf);
    gemm1_kernel<<<dim3(64, 32), 256, 0, stream>>>(Xbuf, Wt, b1, Hbuf);
    transpose_f32_f16<HID, DIM><<<dim3(DIM / 64, HID / 64, NEXP), 256, 0, stream>>>(W2, Wt);
    gemm2_kernel<<<dim3(64, 8), 256, 0, stream>>>(Hbuf, Wt, b2, s2t, scale, out);
}

// Round 4
// 592.001 us; speedup vs baseline: 5.2459x; 1.0372x over previous
//
#include <hip/hip_runtime.h>
#include <math.h>

#define N_TOK 8192
#define DIM   1024
#define NEXP  8
#define HID   4096
#define CAP   1024
#define TPT   (N_TOK / 256)
#define RT_BLOCKS 1024
#define RT_TPB 8                 // tokens per router block (2 per wave)

typedef _Float16 f16x8 __attribute__((ext_vector_type(8)));
typedef _Float16 f16x4 __attribute__((ext_vector_type(4)));
typedef float    f32x4 __attribute__((ext_vector_type(4)));

// tanh-approx GELU: max |diff vs erf-gelu| ~5e-4; after gemm2 (random W2) -> ~2e-4.
__device__ __forceinline__ float gelu_fast(float v) {
    const float v2 = v * v;
    const float u = v * (0.79788456f + 0.035677408136f * v2);  // sqrt(2/pi)*(v+0.044715v^3)
    const float ex = __expf(2.f * u);
    const float th = 1.f - 2.f / (1.f + ex);                   // tanh(u), saturates correctly
    return 0.5f * v * (1.f + th);
}

__device__ __forceinline__ void gl_lds16(const void* g, void* l) {
    __builtin_amdgcn_global_load_lds(
        (const __attribute__((address_space(1))) unsigned int*)g,
        (__attribute__((address_space(3))) unsigned int*)l, 16, 0, 0);
}

// ---------------- router: 1024 blocks, float4 x-loads, per-block partials ----------------
__global__ __launch_bounds__(256) void router_kernel(
    const float* __restrict__ x, const float* __restrict__ Wg,
    int* __restrict__ ei, float* __restrict__ eprob,
    float* __restrict__ pp)            // [RT_BLOCKS][NEXP+1]
{
    __shared__ float psum_s[NEXP + 1];
    const int tid = threadIdx.x;
    const int w = tid >> 6, lane = tid & 63;
    if (tid <= NEXP) psum_s[tid] = 0.f;
    __syncthreads();

    float p_loc[NEXP];
#pragma unroll
    for (int e = 0; e < NEXP; ++e) p_loc[e] = 0.f;
    float z_loc = 0.f;

#pragma unroll
    for (int ti = 0; ti < 2; ++ti) {
        const int t = blockIdx.x * RT_TPB + w * 2 + ti;
        const float* xr = x + (size_t)t * DIM;
        float acc[NEXP];
#pragma unroll
        for (int e = 0; e < NEXP; ++e) acc[e] = 0.f;
#pragma unroll
        for (int k = 0; k < DIM / 256; ++k) {           // 4 iters, independent loads
            const int d = k * 256 + lane * 4;
            const float4 xv = *(const float4*)(xr + d);
            const float xs[4] = {xv.x, xv.y, xv.z, xv.w};
#pragma unroll
            for (int u = 0; u < 4; ++u) {
                const float4 w0 = *(const float4*)(Wg + (size_t)(d + u) * NEXP);
                const float4 w1 = *(const float4*)(Wg + (size_t)(d + u) * NEXP + 4);
                acc[0] += xs[u] * w0.x; acc[1] += xs[u] * w0.y;
                acc[2] += xs[u] * w0.z; acc[3] += xs[u] * w0.w;
                acc[4] += xs[u] * w1.x; acc[5] += xs[u] * w1.y;
                acc[6] += xs[u] * w1.z; acc[7] += xs[u] * w1.w;
            }
        }
#pragma unroll
        for (int off = 32; off > 0; off >>= 1) {
#pragma unroll
            for (int e = 0; e < NEXP; ++e)
                acc[e] += __shfl_down(acc[e], off, 64);
        }
        if (lane == 0) {
            float m = acc[0]; int arg = 0;
#pragma unroll
            for (int e = 1; e < NEXP; ++e) { if (acc[e] > m) { m = acc[e]; arg = e; } }
            float ex[NEXP]; float se = 0.f;
#pragma unroll
            for (int e = 0; e < NEXP; ++e) { ex[e] = expf(acc[e] - m); se += ex[e]; }
            const float lse = m + logf(se);
            const float inv = 1.f / se;
#pragma unroll
            for (int e = 0; e < NEXP; ++e) p_loc[e] += ex[e] * inv;
            z_loc += lse * lse;
            ei[t] = arg;
            eprob[t] = ex[arg] * inv;
        }
    }
    if (lane == 0) {
#pragma unroll
        for (int e = 0; e < NEXP; ++e) atomicAdd(&psum_s[e], p_loc[e]);
        atomicAdd(&psum_s[NEXP], z_loc);
    }
    __syncthreads();
    if (tid <= NEXP) pp[blockIdx.x * (NEXP + 1) + tid] = psum_s[tid];
}

// ---------------- dispatch ----------------
__global__ __launch_bounds__(256) void dispatch_kernel(
    const int* __restrict__ ei, const float* __restrict__ eprob,
    int* __restrict__ slot_to_token, int* __restrict__ sort_idx,
    float* __restrict__ scale,
    const float* __restrict__ pp,      // [RT_BLOCKS][NEXP+1]
    int* __restrict__ dropped, int* __restrict__ n_dropped,
    float* __restrict__ aux_out)
{
    __shared__ int hist[NEXP][256];
    __shared__ int start_s[NEXP];
    __shared__ float red_s[4][NEXP + 1];
    __shared__ float tot_s[NEXP + 1];
    __shared__ int ndrop_s;
    const int t = threadIdx.x;
    const int w = t >> 6, lane = t & 63;
    if (t == 0) ndrop_s = 0;

    // reduce router partials: 1024 blocks -> each thread sums 4
    {
        float v[NEXP + 1];
#pragma unroll
        for (int j = 0; j <= NEXP; ++j) v[j] = 0.f;
        for (int g = 0; g < RT_BLOCKS / 256; ++g)
#pragma unroll
            for (int j = 0; j <= NEXP; ++j) v[j] += pp[(size_t)(g * 256 + t) * (NEXP + 1) + j];
#pragma unroll
        for (int j = 0; j <= NEXP; ++j) {
            float s = v[j];
#pragma unroll
            for (int off = 32; off > 0; off >>= 1) s += __shfl_down(s, off, 64);
            if (lane == 0) red_s[w][j] = s;
        }
    }
    __syncthreads();
    if (t <= NEXP) tot_s[t] = red_s[0][t] + red_s[1][t] + red_s[2][t] + red_s[3][t];
    __syncthreads();

    int le[TPT];
    int lh[NEXP];
#pragma unroll
    for (int e = 0; e < NEXP; ++e) lh[e] = 0;
    const int base = t * TPT;
    for (int i = 0; i < TPT; ++i) {
        const int e = ei[base + i];
        le[i] = e;
        lh[e]++;
    }
#pragma unroll
    for (int e = 0; e < NEXP; ++e) hist[e][t] = lh[e];
    __syncthreads();
    for (int off = 1; off < 256; off <<= 1) {
        int v[NEXP];
#pragma unroll
        for (int e = 0; e < NEXP; ++e) v[e] = (t >= off) ? hist[e][t - off] : 0;
        __syncthreads();
#pragma unroll
        for (int e = 0; e < NEXP; ++e) hist[e][t] += v[e];
        __syncthreads();
    }
    if (t == 0) {
        int s = 0;
        for (int e = 0; e < NEXP; ++e) { start_s[e] = s; s += hist[e][255]; }
    }
    __syncthreads();
    int run[NEXP];
#pragma unroll
    for (int e = 0; e < NEXP; ++e) run[e] = (t > 0) ? hist[e][t - 1] : 0;
    for (int i = 0; i < TPT; ++i) {
        const int n = base + i;
        const int e = le[i];
        const int pos = run[e]++;
        sort_idx[start_s[e] + pos] = n;
        if (pos < CAP) {
            slot_to_token[e * CAP + pos] = n;
        } else {
            const int di = atomicAdd(&ndrop_s, 1);
            dropped[di] = n;
        }
    }
    __syncthreads();
    for (int n = t; n < N_TOK; n += 256) scale[n] = eprob[sort_idx[n]];
    if (t == 0) {
        n_dropped[0] = ndrop_s;
        float s = 0.f;
        for (int e = 0; e < NEXP; ++e) {
            const float f = (float)hist[e][255] / (float)N_TOK;
            const float p = tot_s[e] / (float)N_TOK;
            s += f * p;
        }
        aux_out[0] = 0.01f * (float)NEXP * s + 0.001f * (tot_s[NEXP] / (float)N_TOK);
    }
}

// ---------------- zero only the dropped token rows ----------------
__global__ __launch_bounds__(256) void zero_dropped_kernel(
    const int* __restrict__ dropped, const int* __restrict__ n_dropped,
    float* __restrict__ out)
{
    const int nd = n_dropped[0];
    const float4 z = make_float4(0.f, 0.f, 0.f, 0.f);
    for (int idx = blockIdx.x; idx < nd; idx += gridDim.x) {
        const int tok = dropped[idx];
        *(float4*)(out + (size_t)tok * DIM + threadIdx.x * 4) = z;
    }
}

// ---------------- gather tokens into per-expert fp16 buffer ----------------
__global__ __launch_bounds__(256) void gather_kernel(
    const float* __restrict__ x, const int* __restrict__ slot_to_token,
    _Float16* __restrict__ Xbuf)
{
    const int slot = blockIdx.x;
    const int tok = slot_to_token[slot];
    const int c = threadIdx.x * 4;
    float4 v = make_float4(0.f, 0.f, 0.f, 0.f);
    if (tok >= 0) v = *(const float4*)(x + (size_t)tok * DIM + c);
    f16x4 o;
    o[0] = (_Float16)v.x; o[1] = (_Float16)v.y;
    o[2] = (_Float16)v.z; o[3] = (_Float16)v.w;
    *(f16x4*)(Xbuf + (size_t)slot * DIM + c) = o;
}

// ---------------- fp32 [E][R][C] -> fp16 [E][C][R] transpose ----------------
template<int R, int C>
__global__ __launch_bounds__(256) void transpose_f32_f16(
    const float* __restrict__ in, _Float16* __restrict__ outT)
{
    const int e = blockIdx.z;
    const int r0 = blockIdx.y * 64, c0 = blockIdx.x * 64;
    const float* pin = in + (size_t)e * R * C;
    _Float16* pot = outT + (size_t)e * R * C;
    __shared__ _Float16 tile[64][72];
    const int tid = threadIdx.x;
    const int rr = tid >> 4, cc = (tid & 15) * 4;
#pragma unroll
    for (int ri = 0; ri < 4; ++ri) {
        const int row = rr + ri * 16;
        const float4 v = *(const float4*)&pin[(size_t)(r0 + row) * C + c0 + cc];
        tile[cc + 0][row] = (_Float16)v.x;
        tile[cc + 1][row] = (_Float16)v.y;
        tile[cc + 2][row] = (_Float16)v.z;
        tile[cc + 3][row] = (_Float16)v.w;
    }
    __syncthreads();
    const int c = tid >> 2, rs = (tid & 3) * 16;
    const f16x8 o0 = *(const f16x8*)&tile[c][rs];
    const f16x8 o1 = *(const f16x8*)&tile[c][rs + 8];
    _Float16* po = &pot[(size_t)(c0 + c) * R + r0 + rs];
    *(f16x8*)po = o0;
    *(f16x8*)(po + 8) = o1;
}

// ---------------- MFMA GEMM 1: Hbuf = gelu(Xbuf @ W1 + b1), fp16 ----------------
// XOR-swizzled LDS (seg' = seg ^ (row&3)) to break 8-way b128 read conflicts.
__global__ __launch_bounds__(256) void gemm1_kernel(
    const _Float16* __restrict__ A, const _Float16* __restrict__ Bt,
    const float* __restrict__ b1, _Float16* __restrict__ Hbuf)
{
    // XCD-partitioned block swizzle: each XCD (b&7) owns 4 nb columns -> B L2-resident
    const int b = blockIdx.x;
    const int xcd = b & 7, q = b >> 3;
    const int nb = (xcd << 2) | (q & 3);     // 0..31
    const int mb = q >> 2;                   // 0..63
    const int e  = mb >> 3;
    const _Float16* Ab = A  + (size_t)mb * 128 * DIM;
    const _Float16* Bb = Bt + (size_t)e * HID * DIM + (size_t)nb * 128 * DIM;
    __shared__ _Float16 As[128 * 32];
    __shared__ _Float16 Bs[128 * 32];
    const int tid = threadIdx.x;
    const int lane = tid & 63, w = tid >> 6;
    const int wm = (w >> 1) * 64, wn = (w & 1) * 64;
    const int lr = lane & 15, quad = lane >> 4;

    f32x4 acc[4][4];
#pragma unroll
    for (int i = 0; i < 4; ++i)
#pragma unroll
        for (int j = 0; j < 4; ++j) acc[i][j] = (f32x4)0.f;

    for (int k0 = 0; k0 < DIM; k0 += 32) {
#pragma unroll
        for (int i = 0; i < 2; ++i) {
            const int idx = i * 256 + tid;
            const int row = idx >> 2, s = idx & 3;
            const int seg = s ^ (row & 3);               // store-side swizzle
            gl_lds16(Ab + (size_t)row * DIM + k0 + seg * 8, &As[idx * 8]);
            gl_lds16(Bb + (size_t)row * DIM + k0 + seg * 8, &Bs[idx * 8]);
        }
        __syncthreads();
        f16x8 af[4], bf[4];
#pragma unroll
        for (int i = 0; i < 4; ++i) {
            const int R = wm + i * 16 + lr;
            af[i] = *(const f16x8*)&As[R * 32 + (quad ^ (R & 3)) * 8];
        }
#pragma unroll
        for (int j = 0; j < 4; ++j) {
            const int R = wn + j * 16 + lr;
            bf[j] = *(const f16x8*)&Bs[R * 32 + (quad ^ (R & 3)) * 8];
        }
#pragma unroll
        for (int i = 0; i < 4; ++i)
#pragma unroll
            for (int j = 0; j < 4; ++j)
                acc[i][j] = __builtin_amdgcn_mfma_f32_16x16x32_f16(af[i], bf[j], acc[i][j], 0, 0, 0);
        __syncthreads();
    }
    float bias[4];
#pragma unroll
    for (int j = 0; j < 4; ++j)
        bias[j] = b1[(size_t)e * HID + (size_t)nb * 128 + wn + j * 16 + lr];
#pragma unroll
    for (int i = 0; i < 4; ++i) {
#pragma unroll
        for (int r = 0; r < 4; ++r) {
            const size_t row = (size_t)mb * 128 + wm + i * 16 + quad * 4 + r;
            _Float16* hr = Hbuf + row * HID + (size_t)nb * 128;
#pragma unroll
            for (int j = 0; j < 4; ++j)
                hr[wn + j * 16 + lr] = (_Float16)gelu_fast(acc[i][j][r] + bias[j]);
        }
    }
}

// ---------------- MFMA GEMM 2: out[tok] = (Hbuf @ W2 + b2) * scale ----------------
__global__ __launch_bounds__(256) void gemm2_kernel(
    const _Float16* __restrict__ A, const _Float16* __restrict__ Bt,
    const float* __restrict__ b2, const int* __restrict__ slot_to_token,
    const float* __restrict__ scale, float* __restrict__ out)
{
    const int mb = blockIdx.x;
    const int nb = blockIdx.y;
    const int e  = mb >> 3;
    const _Float16* Ab = A  + (size_t)mb * 128 * HID;
    const _Float16* Bb = Bt + (size_t)e * DIM * HID + (size_t)nb * 128 * HID;
    __shared__ _Float16 As[128 * 32];
    __shared__ _Float16 Bs[128 * 32];
    const int tid = threadIdx.x;
    const int lane = tid & 63, w = tid >> 6;
    const int wm = (w >> 1) * 64, wn = (w & 1) * 64;
    const int lr = lane & 15, quad = lane >> 4;

    f32x4 acc[4][4];
#pragma unroll
    for (int i = 0; i < 4; ++i)
#pragma unroll
        for (int j = 0; j < 4; ++j) acc[i][j] = (f32x4)0.f;

    for (int k0 = 0; k0 < HID; k0 += 32) {
#pragma unroll
        for (int i = 0; i < 2; ++i) {
            const int idx = i * 256 + tid;
            const int row = idx >> 2, s = idx & 3;
            const int seg = s ^ (row & 3);
            gl_lds16(Ab + (size_t)row * HID + k0 + seg * 8, &As[idx * 8]);
            gl_lds16(Bb + (size_t)row * HID + k0 + seg * 8, &Bs[idx * 8]);
        }
        __syncthreads();
        f16x8 af[4], bf[4];
#pragma unroll
        for (int i = 0; i < 4; ++i) {
            const int R = wm + i * 16 + lr;
            af[i] = *(const f16x8*)&As[R * 32 + (quad ^ (R & 3)) * 8];
        }
#pragma unroll
        for (int j = 0; j < 4; ++j) {
            const int R = wn + j * 16 + lr;
            bf[j] = *(const f16x8*)&Bs[R * 32 + (quad ^ (R & 3)) * 8];
        }
#pragma unroll
        for (int i = 0; i < 4; ++i)
#pragma unroll
            for (int j = 0; j < 4; ++j)
                acc[i][j] = __builtin_amdgcn_mfma_f32_16x16x32_f16(af[i], bf[j], acc[i][j], 0, 0, 0);
        __syncthreads();
    }
    float bias[4];
#pragma unroll
    for (int j = 0; j < 4; ++j)
        bias[j] = b2[(size_t)e * DIM + (size_t)nb * 128 + wn + j * 16 + lr];
#pragma unroll
    for (int i = 0; i < 4; ++i) {
#pragma unroll
        for (int r = 0; r < 4; ++r) {
            const int slot = mb * 128 + wm + i * 16 + quad * 4 + r;
            const int tok = slot_to_token[slot];
            if (tok >= 0) {
                const float sc = scale[tok];
                float* orow = out + (size_t)tok * DIM + (size_t)nb * 128;
#pragma unroll
                for (int j = 0; j < 4; ++j)
                    orow[wn + j * 16 + lr] = (acc[i][j][r] + bias[j]) * sc;
            }
        }
    }
}

extern "C" void kernel_launch(void* const* d_in, const int* in_sizes, int n_in,
                              void* d_out, int out_size, void* d_ws, size_t ws_size,
                              hipStream_t stream)
{
    const float* x  = (const float*)d_in[0];
    const float* Wg = (const float*)d_in[1];
    const float* W1 = (const float*)d_in[2];
    const float* b1 = (const float*)d_in[3];
    const float* W2 = (const float*)d_in[4];
    const float* b2 = (const float*)d_in[5];
    float* out = (float*)d_out;

    _Float16* Wt   = (_Float16*)d_ws;                         // 64 MB (W1t, later W2t)
    _Float16* Xbuf = Wt + (size_t)NEXP * HID * DIM;           // 16 MB
    _Float16* Hbuf = Xbuf + (size_t)N_TOK * DIM;              // 64 MB
    int*   ei    = (int*)(Hbuf + (size_t)N_TOK * HID);
    float* eprob = (float*)(ei + N_TOK);
    int*   sort_idx = (int*)(eprob + N_TOK);
    float* scale = (float*)(sort_idx + N_TOK);
    int*   s2t   = (int*)(scale + N_TOK);
    float* pp    = (float*)(s2t + NEXP * CAP);                // [1024][9]
    int*   dropped = (int*)(pp + RT_BLOCKS * (NEXP + 1));     // [8192]
    int*   n_dropped = dropped + N_TOK;                       // [1]

    hipMemsetAsync(s2t, 0xFF, (size_t)NEXP * CAP * sizeof(int), stream);

    transpose_f32_f16<DIM, HID><<<dim3(HID / 64, DIM / 64, NEXP), 256, 0, stream>>>(W1, Wt);
    router_kernel<<<RT_BLOCKS, 256, 0, stream>>>(x, Wg, ei, eprob, pp);
    dispatch_kernel<<<1, 256, 0, stream>>>(ei, eprob, s2t, sort_idx, scale,
                                           pp, dropped, n_dropped,
                                           out + (size_t)N_TOK * DIM);
    zero_dropped_kernel<<<128, 256, 0, stream>>>(dropped, n_dropped, out);
    gather_kernel<<<NEXP * CAP, 256, 0, stream>>>(x, s2t, Xbuf);
    gemm1_kernel<<<2048, 256, 0, stream>>>(Xbuf, Wt, b1, Hbuf);
    transpose_f32_f16<HID, DIM><<<dim3(DIM / 64, HID / 64, NEXP), 256, 0, stream>>>(W2, Wt);
    gemm2_kernel<<<dim3(64, 8), 256, 0, stream>>>(Hbuf, Wt, b2, s2t, scale, out);
}